// Round 1
// baseline (754.712 us; speedup 1.0000x reference)
//
#include <hip/hip_runtime.h>
#include <math.h>

#define D 64
#define BN_EPS 1e-5f

// ---------------- fused 4-GEMM: K = xWk+bk, Q = xWq+bq, V = xWv+bv, AGG = xWs+bs+bias ----------------
// One block = 256 threads = 4 waves, processes a 64-row tile.
// lane -> output column c; wave rg -> rows rg*16..rg*16+15.
__global__ __launch_bounds__(256) void gemm_fused(
    const float* __restrict__ x,
    const float* __restrict__ Wk, const float* __restrict__ bk,
    const float* __restrict__ Wq, const float* __restrict__ bq,
    const float* __restrict__ Wv, const float* __restrict__ bv,
    const float* __restrict__ Ws, const float* __restrict__ bs,
    const float* __restrict__ bias,
    float* __restrict__ K, float* __restrict__ Q, float* __restrict__ V,
    float* __restrict__ AGG, int nrows)
{
    __shared__ float xt[64 * D];
    const int t = threadIdx.x;
    const int row0 = blockIdx.x * 64;

    // stage x tile [64][64] via float4 (coalesced, conflict-free b128 writes)
    #pragma unroll
    for (int i = 0; i < 4; ++i) {
        int fidx = t + i * 256;          // float4 index within tile [0,1024)
        int r = fidx >> 4;
        int c4 = fidx & 15;
        int grow = row0 + r;
        float4 v = make_float4(0.f, 0.f, 0.f, 0.f);
        if (grow < nrows)
            v = *reinterpret_cast<const float4*>(&x[(size_t)grow * D + c4 * 4]);
        *reinterpret_cast<float4*>(&xt[fidx * 4]) = v;
    }
    __syncthreads();

    const int c  = t & 63;
    const int rg = t >> 6;

    float aK[16], aQ[16], aV[16], aS[16];
    #pragma unroll
    for (int r = 0; r < 16; ++r) { aK[r] = 0.f; aQ[r] = 0.f; aV[r] = 0.f; aS[r] = 0.f; }

    for (int k4 = 0; k4 < 16; ++k4) {
        float wk[4], wq[4], wv[4], wsv[4];
        #pragma unroll
        for (int j = 0; j < 4; ++j) {
            int kk = k4 * 4 + j;
            wk[j]  = Wk[kk * D + c];
            wq[j]  = Wq[kk * D + c];
            wv[j]  = Wv[kk * D + c];
            wsv[j] = Ws[kk * D + c];
        }
        #pragma unroll
        for (int r = 0; r < 16; ++r) {
            // uniform-address LDS read (broadcast, conflict-free)
            float4 xv = *reinterpret_cast<const float4*>(&xt[(rg * 16 + r) * D + k4 * 4]);
            aK[r] = fmaf(xv.x, wk[0],  fmaf(xv.y, wk[1],  fmaf(xv.z, wk[2],  fmaf(xv.w, wk[3],  aK[r]))));
            aQ[r] = fmaf(xv.x, wq[0],  fmaf(xv.y, wq[1],  fmaf(xv.z, wq[2],  fmaf(xv.w, wq[3],  aQ[r]))));
            aV[r] = fmaf(xv.x, wv[0],  fmaf(xv.y, wv[1],  fmaf(xv.z, wv[2],  fmaf(xv.w, wv[3],  aV[r]))));
            aS[r] = fmaf(xv.x, wsv[0], fmaf(xv.y, wsv[1], fmaf(xv.z, wsv[2], fmaf(xv.w, wsv[3], aS[r]))));
        }
    }

    const float bkc = bk[c], bqc = bq[c], bvc = bv[c], bsc = bs[c] + bias[c];
    #pragma unroll
    for (int r = 0; r < 16; ++r) {
        int grow = row0 + rg * 16 + r;
        if (grow < nrows) {
            size_t o = (size_t)grow * D + c;
            K[o]   = aK[r] + bkc;
            Q[o]   = aQ[r] + bqc;
            V[o]   = aV[r] + bvc;
            AGG[o] = aS[r] + bsc;
        }
    }
}

// ---------------- per-edge: msg = sigmoid(K[dst]+Q[src]) * V[src]; AGG[dst] += msg ----------------
// One wave per edge, lane = feature. 256B coalesced row loads; fp32 global atomics.
__global__ __launch_bounds__(256) void edge_kernel(
    const int* __restrict__ src, const int* __restrict__ dst,
    const float* __restrict__ K, const float* __restrict__ Q,
    const float* __restrict__ V, float* __restrict__ AGG, int nedges)
{
    const int lane = threadIdx.x & 63;
    int wave = (blockIdx.x * blockDim.x + threadIdx.x) >> 6;
    const int nwaves = (gridDim.x * blockDim.x) >> 6;
    for (int e = wave; e < nedges; e += nwaves) {
        int s = src[e];
        int d = dst[e];
        float kd = K[(size_t)d * D + lane];
        float qs = Q[(size_t)s * D + lane];
        float vs = V[(size_t)s * D + lane];
        float z = kd + qs;
        float g = 1.0f / (1.0f + __expf(-z));
        atomicAdd(&AGG[(size_t)d * D + lane], g * vs);
    }
}

// ---------------- stats: per-feature sum / sumsq of relu(AGG) ----------------
__global__ __launch_bounds__(256) void stats_kernel(
    const float* __restrict__ AGG, float* __restrict__ stats, int ntot)
{
    __shared__ float ssum[256], ssq[256];
    const int t = threadIdx.x;
    int idx = blockIdx.x * 256 + t;
    const int stride = gridDim.x * 256;   // multiple of 64 -> each thread owns one feature
    float sum = 0.f, sq = 0.f;
    for (; idx < ntot; idx += stride) {
        float y = fmaxf(AGG[idx], 0.f);
        sum += y;
        sq = fmaf(y, y, sq);
    }
    ssum[t] = sum; ssq[t] = sq;
    __syncthreads();
    if (t < 64) {
        float s4 = ssum[t] + ssum[t + 64] + ssum[t + 128] + ssum[t + 192];
        float q4 = ssq[t]  + ssq[t + 64]  + ssq[t + 128]  + ssq[t + 192];
        atomicAdd(&stats[t], s4);
        atomicAdd(&stats[64 + t], q4);
    }
}

// ---------------- finalize: scale/shift per feature ----------------
__global__ void finalize_stats(float* __restrict__ stats,
                               const float* __restrict__ gamma,
                               const float* __restrict__ beta, int nrows)
{
    int t = threadIdx.x;  // 64 threads
    float invN = 1.0f / (float)nrows;
    float mean = stats[t] * invN;
    float var  = stats[64 + t] * invN - mean * mean;
    float sc   = gamma[t] * rsqrtf(var + BN_EPS);
    stats[128 + t] = sc;
    stats[192 + t] = beta[t] - mean * sc;
}

// ---------------- apply: xout = relu(AGG)*scale + shift ----------------
__global__ __launch_bounds__(256) void apply_bn(
    const float* __restrict__ AGG, const float* __restrict__ stats,
    float* __restrict__ xout, int ntot4)
{
    int idx = blockIdx.x * 256 + threadIdx.x;   // float4 index
    const int stride = gridDim.x * 256;
    for (; idx < ntot4; idx += stride) {
        float4 a = reinterpret_cast<const float4*>(AGG)[idx];
        int f0 = (idx * 4) & 63;
        float4 o;
        o.x = fmaxf(a.x, 0.f) * stats[128 + f0]     + stats[192 + f0];
        o.y = fmaxf(a.y, 0.f) * stats[128 + f0 + 1] + stats[192 + f0 + 1];
        o.z = fmaxf(a.z, 0.f) * stats[128 + f0 + 2] + stats[192 + f0 + 2];
        o.w = fmaxf(a.w, 0.f) * stats[128 + f0 + 3] + stats[192 + f0 + 3];
        reinterpret_cast<float4*>(xout)[idx] = o;
    }
}

extern "C" void kernel_launch(void* const* d_in, const int* in_sizes, int n_in,
                              void* d_out, int out_size, void* d_ws, size_t ws_size,
                              hipStream_t stream)
{
    const float* x     = (const float*)d_in[0];
    const int*   ei    = (const int*)d_in[1];
    // d_in[2] = batch (unused: single graph, BN is over all nodes)
    const float* Wk    = (const float*)d_in[3];
    const float* bk    = (const float*)d_in[4];
    const float* Wq    = (const float*)d_in[5];
    const float* bq    = (const float*)d_in[6];
    const float* Wv    = (const float*)d_in[7];
    const float* bv    = (const float*)d_in[8];
    const float* Ws    = (const float*)d_in[9];
    const float* bs    = (const float*)d_in[10];
    const float* bias  = (const float*)d_in[11];
    const float* gamma = (const float*)d_in[12];
    const float* beta  = (const float*)d_in[13];

    const int nrows  = in_sizes[0] / D;     // 100000
    const int nedges = in_sizes[1] / 2;     // 1250000
    const int nm     = nrows * D;           // 6,400,000

    float* out = (float*)d_out;
    float* ws  = (float*)d_ws;
    float* K   = ws;
    float* Q   = K + nm;
    float* V   = Q + nm;
    float* AGG = V + nm;
    float* stats = AGG + nm;                // 256 floats

    const int* srcI = ei;                   // edge_index[0] = source j
    const int* dstI = ei + nedges;          // edge_index[1] = target i

    const int gemm_blocks = (nrows + 63) / 64;

    const float* xin = x;
    for (int l = 0; l < 2; ++l) {
        gemm_fused<<<gemm_blocks, 256, 0, stream>>>(xin,
            Wk + l * D * D, bk + l * D, Wq + l * D * D, bq + l * D,
            Wv + l * D * D, bv + l * D, Ws + l * D * D, bs + l * D,
            bias + l * D, K, Q, V, AGG, nrows);

        edge_kernel<<<2048, 256, 0, stream>>>(srcI, dstI, K, Q, V, AGG, nedges);

        hipMemsetAsync(stats, 0, 128 * sizeof(float), stream);
        stats_kernel<<<1024, 256, 0, stream>>>(AGG, stats, nm);
        finalize_stats<<<1, 64, 0, stream>>>(stats, gamma + l * D, beta + l * D, nrows);
        apply_bn<<<2048, 256, 0, stream>>>(AGG, stats, out, nm / 4);

        xin = out;   // layer 2 reads layer-1 output from d_out
    }
}

// Round 2
// 530.225 us; speedup vs baseline: 1.4234x; 1.4234x over previous
//
#include <hip/hip_runtime.h>
#include <math.h>

#define D 64
#define BN_EPS 1e-5f

static __device__ __forceinline__ float bf2f(unsigned short u) {
    return __uint_as_float(((unsigned int)u) << 16);
}
static __device__ __forceinline__ unsigned short f2bf(float f) {
    unsigned int u = __float_as_uint(f);
    unsigned int r = (u + 0x7fffu + ((u >> 16) & 1u)) >> 16;
    return (unsigned short)r;
}

// ---------------- fused 4-GEMM: K = xWk+bk (f32), QV = bf16 packed, AGG = xWs+bs+bias ----------------
// If APPLY_BN: input x is layer-1's post-relu y; normalize with stats[128..255] while staging.
template<bool APPLY_BN>
__global__ __launch_bounds__(256) void gemm_fused(
    const float* x,                       // no __restrict__: may alias AGG (in-place, own rows only)
    const float* __restrict__ Wk, const float* __restrict__ bk,
    const float* __restrict__ Wq, const float* __restrict__ bq,
    const float* __restrict__ Wv, const float* __restrict__ bv,
    const float* __restrict__ Ws, const float* __restrict__ bs,
    const float* __restrict__ bias, const float* __restrict__ stats,
    float* __restrict__ K, unsigned short* __restrict__ QV,
    float* AGG, int nrows)
{
    __shared__ float xt[64 * D];
    const int t = threadIdx.x;
    const int row0 = blockIdx.x * 64;

    #pragma unroll
    for (int i = 0; i < 4; ++i) {
        int fidx = t + i * 256;          // float4 index within tile [0,1024)
        int r = fidx >> 4;
        int c4 = fidx & 15;
        int grow = row0 + r;
        float4 v = make_float4(0.f, 0.f, 0.f, 0.f);
        if (grow < nrows)
            v = *reinterpret_cast<const float4*>(&x[(size_t)grow * D + c4 * 4]);
        if (APPLY_BN) {
            const float4* st4 = reinterpret_cast<const float4*>(stats);
            float4 sc = st4[32 + c4];
            float4 sh = st4[48 + c4];
            v.x = v.x * sc.x + sh.x;
            v.y = v.y * sc.y + sh.y;
            v.z = v.z * sc.z + sh.z;
            v.w = v.w * sc.w + sh.w;
        }
        *reinterpret_cast<float4*>(&xt[fidx * 4]) = v;
    }
    __syncthreads();

    const int c  = t & 63;
    const int rg = t >> 6;

    float aK[16], aQ[16], aV[16], aS[16];
    #pragma unroll
    for (int r = 0; r < 16; ++r) { aK[r] = 0.f; aQ[r] = 0.f; aV[r] = 0.f; aS[r] = 0.f; }

    for (int k4 = 0; k4 < 16; ++k4) {
        float wk[4], wq[4], wv[4], wsv[4];
        #pragma unroll
        for (int j = 0; j < 4; ++j) {
            int kk = k4 * 4 + j;
            wk[j]  = Wk[kk * D + c];
            wq[j]  = Wq[kk * D + c];
            wv[j]  = Wv[kk * D + c];
            wsv[j] = Ws[kk * D + c];
        }
        #pragma unroll
        for (int r = 0; r < 16; ++r) {
            float4 xv = *reinterpret_cast<const float4*>(&xt[(rg * 16 + r) * D + k4 * 4]);
            aK[r] = fmaf(xv.x, wk[0],  fmaf(xv.y, wk[1],  fmaf(xv.z, wk[2],  fmaf(xv.w, wk[3],  aK[r]))));
            aQ[r] = fmaf(xv.x, wq[0],  fmaf(xv.y, wq[1],  fmaf(xv.z, wq[2],  fmaf(xv.w, wq[3],  aQ[r]))));
            aV[r] = fmaf(xv.x, wv[0],  fmaf(xv.y, wv[1],  fmaf(xv.z, wv[2],  fmaf(xv.w, wv[3],  aV[r]))));
            aS[r] = fmaf(xv.x, wsv[0], fmaf(xv.y, wsv[1], fmaf(xv.z, wsv[2], fmaf(xv.w, wsv[3], aS[r]))));
        }
    }

    const float bkc = bk[c], bqc = bq[c], bvc = bv[c], bsc = bs[c] + bias[c];
    #pragma unroll
    for (int r = 0; r < 16; ++r) {
        int grow = row0 + rg * 16 + r;
        if (grow < nrows) {
            size_t o = (size_t)grow * D + c;
            K[o]   = aK[r] + bkc;
            QV[(size_t)grow * 128 + c]      = f2bf(aQ[r] + bqc);
            QV[(size_t)grow * 128 + 64 + c] = f2bf(aV[r] + bvc);
            AGG[o] = aS[r] + bsc;
        }
    }
}

// ---------------- CSR build ----------------
__global__ __launch_bounds__(256) void hist_kernel(const int* __restrict__ dst,
                                                   int* __restrict__ counts, int nedges)
{
    int i = blockIdx.x * 256 + threadIdx.x;
    if (i < nedges) atomicAdd(&counts[dst[i]], 1);
}

// block-local exclusive scan (256/block), emit block sums
__global__ __launch_bounds__(256) void scan1(const int* __restrict__ counts,
                                             int* __restrict__ offs,
                                             int* __restrict__ bsums, int n)
{
    __shared__ int tmp[256];
    const int t = threadIdx.x;
    const int i = blockIdx.x * 256 + t;
    int v = (i < n) ? counts[i] : 0;
    tmp[t] = v;
    __syncthreads();
    for (int off = 1; off < 256; off <<= 1) {
        int add = (t >= off) ? tmp[t - off] : 0;
        __syncthreads();
        tmp[t] += add;
        __syncthreads();
    }
    if (i < n) offs[i] = tmp[t] - v;   // exclusive
    if (t == 255) bsums[blockIdx.x] = tmp[255];
}

// scan the block sums (nb <= 512), in place, exclusive
__global__ __launch_bounds__(512) void scan2(int* __restrict__ bsums, int nb)
{
    __shared__ int tmp[512];
    const int t = threadIdx.x;
    int v = (t < nb) ? bsums[t] : 0;
    tmp[t] = v;
    __syncthreads();
    for (int off = 1; off < 512; off <<= 1) {
        int add = (t >= off) ? tmp[t - off] : 0;
        __syncthreads();
        tmp[t] += add;
        __syncthreads();
    }
    if (t < nb) bsums[t] = tmp[t] - v;
}

__global__ __launch_bounds__(256) void scan3(int* __restrict__ offs,
                                             const int* __restrict__ bsums,
                                             int* __restrict__ cursor,
                                             int n, int nedges)
{
    int i = blockIdx.x * 256 + threadIdx.x;
    if (i < n) {
        int o = offs[i] + bsums[blockIdx.x];
        offs[i] = o;
        cursor[i] = o;
    }
    if (i == 0) offs[n] = nedges;
}

__global__ __launch_bounds__(256) void scatter_kernel(const int* __restrict__ src,
                                                      const int* __restrict__ dst,
                                                      int* __restrict__ cursor,
                                                      int* __restrict__ csr_src, int nedges)
{
    int i = blockIdx.x * 256 + threadIdx.x;
    if (i < nedges) {
        int d = dst[i];
        int pos = atomicAdd(&cursor[d], 1);
        csr_src[pos] = src[i];
    }
}

// ---------------- aggregation + ReLU + BN-stats: one wave per dst node ----------------
__global__ __launch_bounds__(256) void agg_stats(
    const int* __restrict__ csr_src, const int* __restrict__ offs,
    const float* __restrict__ K, const unsigned short* __restrict__ QV,
    float* __restrict__ AGG, float* __restrict__ stats, int nnodes)
{
    const int lane = threadIdx.x & 63;
    const int wave = (blockIdx.x * 256 + threadIdx.x) >> 6;
    const int nwaves = (gridDim.x * 256) >> 6;

    float lsum = 0.f, lsq = 0.f;
    for (int node = wave; node < nnodes; node += nwaves) {
        const int beg = offs[node];
        const int end = offs[node + 1];
        float kd  = K[node * D + lane];
        float acc = AGG[node * D + lane];
        for (int chunk = beg; chunk < end; chunk += 64) {
            int e = chunk + lane;
            int sAll = (e < end) ? csr_src[e] : 0;
            int cnt = min(64, end - chunk);
            for (int j = 0; j < cnt; ++j) {
                int s = __shfl(sAll, j);
                float q = bf2f(QV[s * 128 + lane]);
                float v = bf2f(QV[s * 128 + 64 + lane]);
                float g = 1.0f / (1.0f + __expf(-(kd + q)));
                acc = fmaf(g, v, acc);
            }
        }
        float y = fmaxf(acc, 0.f);
        AGG[node * D + lane] = y;
        lsum += y;
        lsq = fmaf(y, y, lsq);
    }

    __shared__ float ss[256], sq2[256];
    ss[threadIdx.x] = lsum;
    sq2[threadIdx.x] = lsq;
    __syncthreads();
    if (threadIdx.x < 64) {
        float s4 = ss[threadIdx.x] + ss[threadIdx.x + 64] + ss[threadIdx.x + 128] + ss[threadIdx.x + 192];
        float q4 = sq2[threadIdx.x] + sq2[threadIdx.x + 64] + sq2[threadIdx.x + 128] + sq2[threadIdx.x + 192];
        atomicAdd(&stats[threadIdx.x], s4);
        atomicAdd(&stats[64 + threadIdx.x], q4);
    }
}

// ---------------- finalize: scale/shift per feature ----------------
__global__ void finalize_stats(float* __restrict__ stats,
                               const float* __restrict__ gamma,
                               const float* __restrict__ beta, int nrows)
{
    int t = threadIdx.x;  // 64 threads
    float invN = 1.0f / (float)nrows;
    float mean = stats[t] * invN;
    float var  = stats[64 + t] * invN - mean * mean;
    float sc   = gamma[t] * rsqrtf(var + BN_EPS);
    stats[128 + t] = sc;
    stats[192 + t] = beta[t] - mean * sc;
}

// ---------------- apply (final layer only): out = y*scale + shift ----------------
__global__ __launch_bounds__(256) void apply_bn(
    const float* __restrict__ AGG, const float* __restrict__ stats,
    float* __restrict__ xout, int ntot4)
{
    int idx = blockIdx.x * 256 + threadIdx.x;   // float4 index
    const int stride = gridDim.x * 256;
    const float4* st4 = reinterpret_cast<const float4*>(stats);
    for (; idx < ntot4; idx += stride) {
        float4 a = reinterpret_cast<const float4*>(AGG)[idx];
        int c4 = idx & 15;
        float4 sc = st4[32 + c4];
        float4 sh = st4[48 + c4];
        float4 o;
        o.x = a.x * sc.x + sh.x;
        o.y = a.y * sc.y + sh.y;
        o.z = a.z * sc.z + sh.z;
        o.w = a.w * sc.w + sh.w;
        reinterpret_cast<float4*>(xout)[idx] = o;
    }
}

extern "C" void kernel_launch(void* const* d_in, const int* in_sizes, int n_in,
                              void* d_out, int out_size, void* d_ws, size_t ws_size,
                              hipStream_t stream)
{
    const float* x     = (const float*)d_in[0];
    const int*   ei    = (const int*)d_in[1];
    const float* Wk    = (const float*)d_in[3];
    const float* bk    = (const float*)d_in[4];
    const float* Wq    = (const float*)d_in[5];
    const float* bq    = (const float*)d_in[6];
    const float* Wv    = (const float*)d_in[7];
    const float* bv    = (const float*)d_in[8];
    const float* Ws    = (const float*)d_in[9];
    const float* bs    = (const float*)d_in[10];
    const float* bias  = (const float*)d_in[11];
    const float* gamma = (const float*)d_in[12];
    const float* beta  = (const float*)d_in[13];

    const int nrows  = in_sizes[0] / D;     // 100000
    const int nedges = in_sizes[1] / 2;     // 1250000
    const int nm     = nrows * D;

    float* out = (float*)d_out;
    float* ws  = (float*)d_ws;
    float* K   = ws;                                   // nm f32
    unsigned short* QV = (unsigned short*)(K + nm);    // nrows*128 u16 (= nm f32 footprint)
    float* AGG = (float*)(QV) + nm;                    // nm f32
    float* stats = AGG + nm;                           // 256 f32
    int* counts  = (int*)(stats + 256);                // nrows
    int* offs    = counts + nrows;                     // nrows+1
    int* cursor  = offs + nrows + 1;                   // nrows
    int* csr_src = cursor + nrows;                     // nedges

    const int* srcI = ei;
    const int* dstI = ei + nedges;

    const int gemm_blocks = (nrows + 63) / 64;
    const int edge_blocks = (nedges + 255) / 256;
    const int node_blocks = (nrows + 255) / 256;       // 391

    // ---- CSR build (once per call; reused by both layers) ----
    hipMemsetAsync(counts, 0, (size_t)nrows * sizeof(int), stream);
    hist_kernel<<<edge_blocks, 256, 0, stream>>>(dstI, counts, nedges);
    scan1<<<node_blocks, 256, 0, stream>>>(counts, offs, cursor /*tmp bsums*/, nrows);
    // NOTE: reuse `counts` as bsums storage? keep separate: use counts for bsums is unsafe (still needed? no).
    // We reuse `counts` as the block-sums array via a copy-free trick below instead:
    scan2<<<1, 512, 0, stream>>>(cursor, node_blocks);
    scan3<<<node_blocks, 256, 0, stream>>>(offs, cursor, counts /*cursor out*/, nrows, nedges);
    scatter_kernel<<<edge_blocks, 256, 0, stream>>>(srcI, dstI, counts, csr_src, nedges);

    // ---- layer 1 ----
    gemm_fused<false><<<gemm_blocks, 256, 0, stream>>>(x,
        Wk, bk, Wq, bq, Wv, bv, Ws, bs, bias, stats,
        K, QV, AGG, nrows);
    hipMemsetAsync(stats, 0, 128 * sizeof(float), stream);
    agg_stats<<<2048, 256, 0, stream>>>(csr_src, offs, K, QV, AGG, stats, nrows);
    finalize_stats<<<1, 64, 0, stream>>>(stats, gamma, beta, nrows);

    // ---- layer 2 (BN-apply of layer 1 fused into GEMM staging) ----
    gemm_fused<true><<<gemm_blocks, 256, 0, stream>>>(AGG,
        Wk + D * D, bk + D, Wq + D * D, bq + D, Wv + D * D, bv + D,
        Ws + D * D, bs + D, bias + D, stats,
        K, QV, AGG, nrows);
    hipMemsetAsync(stats, 0, 128 * sizeof(float), stream);
    agg_stats<<<2048, 256, 0, stream>>>(csr_src, offs, K, QV, AGG, stats, nrows);
    finalize_stats<<<1, 64, 0, stream>>>(stats, gamma + D, beta + D, nrows);
    apply_bn<<<2048, 256, 0, stream>>>(AGG, stats, out, nm / 4);
}

// Round 3
// 482.558 us; speedup vs baseline: 1.5640x; 1.0988x over previous
//
#include <hip/hip_runtime.h>
#include <math.h>

#define D 64
#define BN_EPS 1e-5f

static __device__ __forceinline__ unsigned short f2bf(float f) {
    unsigned int u = __float_as_uint(f);
    unsigned int r = (u + 0x7fffu + ((u >> 16) & 1u)) >> 16;
    return (unsigned short)r;
}
static __device__ __forceinline__ float clamp60(float x) {
    return fminf(fmaxf(x, -60.f), 60.f);
}

// ---------------- fused 4-GEMM ----------------
// Outputs: EK = exp(-clamp(x@Wk+bk)) f32; QV = packed u32 {bf16(v)<<16 | bf16(exp(-clamp(q)))};
//          AGG = x@Ws+bs+bias (aggregation init).
// If APPLY_BN: input x is layer-1's post-relu y; normalize with stats[128..255] while staging.
template<bool APPLY_BN>
__global__ __launch_bounds__(256) void gemm_fused(
    const float* x,                       // may alias AGG (in-place, own rows only)
    const float* __restrict__ Wk, const float* __restrict__ bk,
    const float* __restrict__ Wq, const float* __restrict__ bq,
    const float* __restrict__ Wv, const float* __restrict__ bv,
    const float* __restrict__ Ws, const float* __restrict__ bs,
    const float* __restrict__ bias, const float* __restrict__ stats,
    float* __restrict__ EK, unsigned int* __restrict__ QV,
    float* AGG, int nrows)
{
    __shared__ float xt[64 * D];
    const int t = threadIdx.x;
    const int row0 = blockIdx.x * 64;

    #pragma unroll
    for (int i = 0; i < 4; ++i) {
        int fidx = t + i * 256;          // float4 index within tile [0,1024)
        int r = fidx >> 4;
        int c4 = fidx & 15;
        int grow = row0 + r;
        float4 v = make_float4(0.f, 0.f, 0.f, 0.f);
        if (grow < nrows)
            v = *reinterpret_cast<const float4*>(&x[(size_t)grow * D + c4 * 4]);
        if (APPLY_BN) {
            const float4* st4 = reinterpret_cast<const float4*>(stats);
            float4 sc = st4[32 + c4];
            float4 sh = st4[48 + c4];
            v.x = v.x * sc.x + sh.x;
            v.y = v.y * sc.y + sh.y;
            v.z = v.z * sc.z + sh.z;
            v.w = v.w * sc.w + sh.w;
        }
        *reinterpret_cast<float4*>(&xt[fidx * 4]) = v;
    }
    __syncthreads();

    const int c  = t & 63;
    const int rg = t >> 6;

    float aK[16], aQ[16], aV[16], aS[16];
    #pragma unroll
    for (int r = 0; r < 16; ++r) { aK[r] = 0.f; aQ[r] = 0.f; aV[r] = 0.f; aS[r] = 0.f; }

    for (int k4 = 0; k4 < 16; ++k4) {
        float wk[4], wq[4], wv[4], wsv[4];
        #pragma unroll
        for (int j = 0; j < 4; ++j) {
            int kk = k4 * 4 + j;
            wk[j]  = Wk[kk * D + c];
            wq[j]  = Wq[kk * D + c];
            wv[j]  = Wv[kk * D + c];
            wsv[j] = Ws[kk * D + c];
        }
        #pragma unroll
        for (int r = 0; r < 16; ++r) {
            float4 xv = *reinterpret_cast<const float4*>(&xt[(rg * 16 + r) * D + k4 * 4]);
            aK[r] = fmaf(xv.x, wk[0],  fmaf(xv.y, wk[1],  fmaf(xv.z, wk[2],  fmaf(xv.w, wk[3],  aK[r]))));
            aQ[r] = fmaf(xv.x, wq[0],  fmaf(xv.y, wq[1],  fmaf(xv.z, wq[2],  fmaf(xv.w, wq[3],  aQ[r]))));
            aV[r] = fmaf(xv.x, wv[0],  fmaf(xv.y, wv[1],  fmaf(xv.z, wv[2],  fmaf(xv.w, wv[3],  aV[r]))));
            aS[r] = fmaf(xv.x, wsv[0], fmaf(xv.y, wsv[1], fmaf(xv.z, wsv[2], fmaf(xv.w, wsv[3], aS[r]))));
        }
    }

    const float bkc = bk[c], bqc = bq[c], bvc = bv[c], bsc = bs[c] + bias[c];
    #pragma unroll
    for (int r = 0; r < 16; ++r) {
        int grow = row0 + rg * 16 + r;
        if (grow < nrows) {
            size_t o = (size_t)grow * D + c;
            EK[o] = __expf(-clamp60(aK[r] + bkc));
            float eq = __expf(-clamp60(aQ[r] + bqc));
            unsigned int pv = ((unsigned int)f2bf(aV[r] + bvc) << 16) | (unsigned int)f2bf(eq);
            QV[o] = pv;
            AGG[o] = aS[r] + bsc;
        }
    }
}

// ---------------- CSR build ----------------
__global__ __launch_bounds__(256) void hist_kernel(const int* __restrict__ dst,
                                                   int* __restrict__ counts, int nedges)
{
    int i = blockIdx.x * 256 + threadIdx.x;
    if (i < nedges) atomicAdd(&counts[dst[i]], 1);
}

__global__ __launch_bounds__(256) void scan1(const int* __restrict__ counts,
                                             int* __restrict__ offs,
                                             int* __restrict__ bsums, int n)
{
    __shared__ int tmp[256];
    const int t = threadIdx.x;
    const int i = blockIdx.x * 256 + t;
    int v = (i < n) ? counts[i] : 0;
    tmp[t] = v;
    __syncthreads();
    for (int off = 1; off < 256; off <<= 1) {
        int add = (t >= off) ? tmp[t - off] : 0;
        __syncthreads();
        tmp[t] += add;
        __syncthreads();
    }
    if (i < n) offs[i] = tmp[t] - v;   // exclusive
    if (t == 255) bsums[blockIdx.x] = tmp[255];
}

__global__ __launch_bounds__(512) void scan2(int* __restrict__ bsums, int nb)
{
    __shared__ int tmp[512];
    const int t = threadIdx.x;
    int v = (t < nb) ? bsums[t] : 0;
    tmp[t] = v;
    __syncthreads();
    for (int off = 1; off < 512; off <<= 1) {
        int add = (t >= off) ? tmp[t - off] : 0;
        __syncthreads();
        tmp[t] += add;
        __syncthreads();
    }
    if (t < nb) bsums[t] = tmp[t] - v;
}

__global__ __launch_bounds__(256) void scan3(int* __restrict__ offs,
                                             const int* __restrict__ bsums,
                                             int* __restrict__ cursor,
                                             float* __restrict__ stats,
                                             int n, int nedges)
{
    int i = blockIdx.x * 256 + threadIdx.x;
    if (i < n) {
        int o = offs[i] + bsums[blockIdx.x];
        offs[i] = o;
        cursor[i] = o;
    }
    if (i == 0) offs[n] = nedges;
    if (i < 128) stats[i] = 0.f;       // zero BN accumulators for layer 1
}

__global__ __launch_bounds__(256) void scatter_kernel(const int* __restrict__ src,
                                                      const int* __restrict__ dst,
                                                      int* __restrict__ cursor,
                                                      int* __restrict__ csr_src, int nedges)
{
    int i = blockIdx.x * 256 + threadIdx.x;
    if (i < nedges) {
        int d = dst[i];
        int pos = atomicAdd(&cursor[d], 1);
        csr_src[pos] = src[i];
    }
}

// ---------------- aggregation + ReLU + BN-stats: one wave per dst node ----------------
// g = 1/(1 + ek*eq);  acc += g*v.  All exp hoisted to gemm.
__global__ __launch_bounds__(256) void agg_stats(
    const int* __restrict__ csr_src, const int* __restrict__ offs,
    const float* __restrict__ EK, const unsigned int* __restrict__ QV,
    float* __restrict__ AGG, float* __restrict__ stats, int nnodes)
{
    const int lane = threadIdx.x & 63;
    const int wave = (blockIdx.x * 256 + threadIdx.x) >> 6;
    const int nwaves = (gridDim.x * 256) >> 6;

    float lsum = 0.f, lsq = 0.f;
    for (int node = wave; node < nnodes; node += nwaves) {
        const int beg = offs[node];
        const int end = offs[node + 1];
        const int ro = (node << 6) | lane;
        float ek  = EK[ro];
        float acc = AGG[ro];
        for (int chunk = beg; chunk < end; chunk += 64) {
            int e = chunk + lane;
            int sAll = (e < end) ? csr_src[e] : 0;
            int cnt = min(64, end - chunk);
            int j = 0;
            for (; j + 8 <= cnt; j += 8) {
                unsigned int p[8];
                #pragma unroll
                for (int u = 0; u < 8; ++u) {
                    int s = __shfl(sAll, j + u);
                    p[u] = QV[(s << 6) | lane];
                }
                #pragma unroll
                for (int u = 0; u < 8; ++u) {
                    float eq = __uint_as_float(p[u] << 16);
                    float vv = __uint_as_float(p[u] & 0xffff0000u);
                    float g  = __builtin_amdgcn_rcpf(fmaf(ek, eq, 1.0f));
                    acc = fmaf(g, vv, acc);
                }
            }
            for (; j < cnt; ++j) {
                int s = __shfl(sAll, j);
                unsigned int p = QV[(s << 6) | lane];
                float eq = __uint_as_float(p << 16);
                float vv = __uint_as_float(p & 0xffff0000u);
                float g  = __builtin_amdgcn_rcpf(fmaf(ek, eq, 1.0f));
                acc = fmaf(g, vv, acc);
            }
        }
        float y = fmaxf(acc, 0.f);
        AGG[ro] = y;
        lsum += y;
        lsq = fmaf(y, y, lsq);
    }

    __shared__ float ss[256], sq2[256];
    ss[threadIdx.x] = lsum;
    sq2[threadIdx.x] = lsq;
    __syncthreads();
    if (threadIdx.x < 64) {
        float s4 = ss[threadIdx.x] + ss[threadIdx.x + 64] + ss[threadIdx.x + 128] + ss[threadIdx.x + 192];
        float q4 = sq2[threadIdx.x] + sq2[threadIdx.x + 64] + sq2[threadIdx.x + 128] + sq2[threadIdx.x + 192];
        atomicAdd(&stats[threadIdx.x], s4);
        atomicAdd(&stats[64 + threadIdx.x], q4);
    }
}

// ---------------- finalize: scale/shift per feature; re-zero sums for next layer ----------------
__global__ void finalize_stats(float* __restrict__ stats,
                               const float* __restrict__ gamma,
                               const float* __restrict__ beta, int nrows)
{
    int t = threadIdx.x;  // 64 threads = 1 wave
    float invN = 1.0f / (float)nrows;
    float mean = stats[t] * invN;
    float var  = stats[64 + t] * invN - mean * mean;
    float sc   = gamma[t] * rsqrtf(var + BN_EPS);
    stats[128 + t] = sc;
    stats[192 + t] = beta[t] - mean * sc;
    stats[t] = 0.f;          // ready for next layer's agg_stats
    stats[64 + t] = 0.f;
}

// ---------------- apply (final layer only): out = y*scale + shift ----------------
__global__ __launch_bounds__(256) void apply_bn(
    const float* __restrict__ AGG, const float* __restrict__ stats,
    float* __restrict__ xout, int ntot4)
{
    int idx = blockIdx.x * 256 + threadIdx.x;   // float4 index
    const int stride = gridDim.x * 256;
    const float4* st4 = reinterpret_cast<const float4*>(stats);
    for (; idx < ntot4; idx += stride) {
        float4 a = reinterpret_cast<const float4*>(AGG)[idx];
        int c4 = idx & 15;
        float4 sc = st4[32 + c4];
        float4 sh = st4[48 + c4];
        float4 o;
        o.x = a.x * sc.x + sh.x;
        o.y = a.y * sc.y + sh.y;
        o.z = a.z * sc.z + sh.z;
        o.w = a.w * sc.w + sh.w;
        reinterpret_cast<float4*>(xout)[idx] = o;
    }
}

extern "C" void kernel_launch(void* const* d_in, const int* in_sizes, int n_in,
                              void* d_out, int out_size, void* d_ws, size_t ws_size,
                              hipStream_t stream)
{
    const float* x     = (const float*)d_in[0];
    const int*   ei    = (const int*)d_in[1];
    const float* Wk    = (const float*)d_in[3];
    const float* bk    = (const float*)d_in[4];
    const float* Wq    = (const float*)d_in[5];
    const float* bq    = (const float*)d_in[6];
    const float* Wv    = (const float*)d_in[7];
    const float* bv    = (const float*)d_in[8];
    const float* Ws    = (const float*)d_in[9];
    const float* bs    = (const float*)d_in[10];
    const float* bias  = (const float*)d_in[11];
    const float* gamma = (const float*)d_in[12];
    const float* beta  = (const float*)d_in[13];

    const int nrows  = in_sizes[0] / D;     // 100000
    const int nedges = in_sizes[1] / 2;     // 1250000
    const int nm     = nrows * D;

    float* out = (float*)d_out;
    float* ws  = (float*)d_ws;
    float* EK  = ws;                                   // nm f32
    unsigned int* QV = (unsigned int*)(EK + nm);       // nm u32
    float* AGG = (float*)(QV + nm);                    // nm f32
    float* stats = AGG + nm;                           // 256 f32
    int* counts  = (int*)(stats + 256);                // nrows
    int* offs    = counts + nrows;                     // nrows+1
    int* cursor  = offs + nrows + 1;                   // nrows
    int* csr_src = cursor + nrows;                     // nedges

    const int* srcI = ei;
    const int* dstI = ei + nedges;

    const int gemm_blocks = (nrows + 63) / 64;
    const int edge_blocks = (nedges + 255) / 256;
    const int node_blocks = (nrows + 255) / 256;       // 391 (<512 for scan2)

    // ---- CSR build (edge_index identical for both layers) ----
    hipMemsetAsync(counts, 0, (size_t)nrows * sizeof(int), stream);
    hist_kernel<<<edge_blocks, 256, 0, stream>>>(dstI, counts, nedges);
    scan1<<<node_blocks, 256, 0, stream>>>(counts, offs, cursor /*bsums tmp*/, nrows);
    scan2<<<1, 512, 0, stream>>>(cursor, node_blocks);
    scan3<<<node_blocks, 256, 0, stream>>>(offs, cursor, counts /*cursor out*/, stats, nrows, nedges);
    scatter_kernel<<<edge_blocks, 256, 0, stream>>>(srcI, dstI, counts, csr_src, nedges);

    // ---- layer 1 ----
    gemm_fused<false><<<gemm_blocks, 256, 0, stream>>>(x,
        Wk, bk, Wq, bq, Wv, bv, Ws, bs, bias, stats,
        EK, QV, AGG, nrows);
    agg_stats<<<2048, 256, 0, stream>>>(counts /*unused pad*/ == nullptr ? nullptr : csr_src, offs, EK, QV, AGG, stats, nrows);
    finalize_stats<<<1, 64, 0, stream>>>(stats, gamma, beta, nrows);

    // ---- layer 2 (BN-apply of layer 1 fused into GEMM staging) ----
    gemm_fused<true><<<gemm_blocks, 256, 0, stream>>>(AGG,
        Wk + D * D, bk + D, Wq + D * D, bq + D, Wv + D * D, bv + D,
        Ws + D * D, bs + D, bias + D, stats,
        EK, QV, AGG, nrows);
    agg_stats<<<2048, 256, 0, stream>>>(csr_src, offs, EK, QV, AGG, stats, nrows);
    finalize_stats<<<1, 64, 0, stream>>>(stats, gamma + D, beta + D, nrows);
    apply_bn<<<2048, 256, 0, stream>>>(AGG, stats, out, nm / 4);
}